// Round 13
// baseline (2089.585 us; speedup 1.0000x reference)
//
#include <hip/hip_runtime.h>
#include <hip/hip_bf16.h>
#include <hip/hip_fp16.h>

#define LNUM 6
#define BB 2
#define TT 1024
#define CC 1024
#define HH 16
#define DHH 64
#define VV 32000
#define MM 128

typedef _Float16 f16;
typedef _Float16 f16x8 __attribute__((ext_vector_type(8)));
typedef float f32x4 __attribute__((ext_vector_type(4)));

__device__ __forceinline__ void g2lds16(const void* g, void* l) {
    __builtin_amdgcn_global_load_lds((const __attribute__((address_space(1))) void*)g,
                                     (__attribute__((address_space(3))) void*)l,
                                     16, 0, 0);
}

__device__ __forceinline__ float wred(float v) {
#pragma unroll
    for (int o = 32; o > 0; o >>= 1) v += __shfl_xor(v, o);
    return v;
}

// ---------------- weight transpose + f32->f16 convert: W (R,Cc) -> WT (Cc,R) ----------------
__global__ __launch_bounds__(256)
void transpose_k(const float* __restrict__ W, f16* __restrict__ WT, int R, int Cc)
{
    __shared__ float tile[64][65];
    const size_t base = (size_t)blockIdx.z * R * Cc;
    const int c0 = blockIdx.x * 64, r0 = blockIdx.y * 64;
    const int tx = threadIdx.x & 15, ty = threadIdx.x >> 4;  // 16 x 16
#pragma unroll
    for (int i = 0; i < 4; ++i) {
        const int row = ty + i * 16;
        float4 v = *(const float4*)&W[base + (size_t)(r0 + row) * Cc + c0 + tx * 4];
        tile[row][tx * 4 + 0] = v.x;
        tile[row][tx * 4 + 1] = v.y;
        tile[row][tx * 4 + 2] = v.z;
        tile[row][tx * 4 + 3] = v.w;
    }
    __syncthreads();
#pragma unroll
    for (int i = 0; i < 4; ++i) {
        const int c = ty + i * 16;
        union { f16 h4[4]; uint2 u; } pk;
        pk.h4[0] = (f16)tile[tx * 4 + 0][c];
        pk.h4[1] = (f16)tile[tx * 4 + 1][c];
        pk.h4[2] = (f16)tile[tx * 4 + 2][c];
        pk.h4[3] = (f16)tile[tx * 4 + 3][c];
        *(uint2*)&WT[base + (size_t)(c0 + c) * R + r0 + tx * 4] = pk.u;
    }
}

// ---------------- embedding gather ----------------
__global__ __launch_bounds__(256)
void embed_k(const int* __restrict__ idx, const float* __restrict__ wte, float* __restrict__ X)
{
    const int row = blockIdx.x;            // B*T rows
    const int id = idx[row];
    const float4* src = (const float4*)(wte + (size_t)id * CC);
    float4* dst = (float4*)(X + (size_t)row * CC);
    dst[threadIdx.x] = src[threadIdx.x];
}

// ---------------- LN (generic, f16 out): one wave per row of C=1024 ----------------
__global__ __launch_bounds__(256)
void ln_k(const float* __restrict__ X, const float* __restrict__ g,
          const float* __restrict__ bta, f16* __restrict__ outH)
{
    const int row = blockIdx.x * 4 + (threadIdx.x >> 6);
    const int lane = threadIdx.x & 63;
    const float4* xr = (const float4*)(X + (size_t)row * CC);
    float4 v[4];
    float s = 0.f;
#pragma unroll
    for (int i = 0; i < 4; ++i) { v[i] = xr[i * 64 + lane]; s += v[i].x + v[i].y + v[i].z + v[i].w; }
    s = wred(s);
    const float mean = s * (1.f / CC);
    float q = 0.f;
#pragma unroll
    for (int i = 0; i < 4; ++i) {
        float a = v[i].x - mean, b = v[i].y - mean, c = v[i].z - mean, d = v[i].w - mean;
        q += a * a + b * b + c * c + d * d;
    }
    q = wred(q);
    const float rs = rsqrtf(q * (1.f / CC) + 1e-5f);
    const float4* g4 = (const float4*)g;
    const float4* b4 = (const float4*)bta;
    uint2* orow = (uint2*)(outH + (size_t)row * CC);
#pragma unroll
    for (int i = 0; i < 4; ++i) {
        float4 gg = g4[i * 64 + lane], bb = b4[i * 64 + lane];
        union { f16 h4[4]; uint2 u; } pk;
        pk.h4[0] = (f16)((v[i].x - mean) * rs * gg.x + bb.x);
        pk.h4[1] = (f16)((v[i].y - mean) * rs * gg.y + bb.y);
        pk.h4[2] = (f16)((v[i].z - mean) * rs * gg.z + bb.z);
        pk.h4[3] = (f16)((v[i].w - mean) * rs * gg.w + bb.w);
        orow[i * 64 + lane] = pk.u;
    }
}

// ---------------- LN1 + concat(mem, ln(x)) + new_mems write ----------------
__global__ __launch_bounds__(256)
void ln1cat_k(const float* __restrict__ X, const float* __restrict__ memsL,
              const float* __restrict__ g, const float* __restrict__ bta,
              f16* __restrict__ catH, float* __restrict__ nmOut,
              int K, int Kin)
{
    const int row = blockIdx.x * 4 + (threadIdx.x >> 6);  // 0..BB*K-1
    const int lane = threadIdx.x & 63;
    const int b = row / K, rr = row % K;
    uint2* crow = (uint2*)(catH + (size_t)row * CC);
    if (rr < MM) {
        const float4* src = (const float4*)(memsL + ((size_t)b * MM + rr) * CC);
#pragma unroll
        for (int i = 0; i < 4; ++i) {
            float4 vv = src[i * 64 + lane];
            union { f16 h4[4]; uint2 u; } pk;
            pk.h4[0] = (f16)vv.x; pk.h4[1] = (f16)vv.y; pk.h4[2] = (f16)vv.z; pk.h4[3] = (f16)vv.w;
            crow[i * 64 + lane] = pk.u;
        }
        return;
    }
    const float4* xr = (const float4*)(X + ((size_t)b * Kin + (rr - MM)) * CC);
    float4 v[4];
    float s = 0.f;
#pragma unroll
    for (int i = 0; i < 4; ++i) { v[i] = xr[i * 64 + lane]; s += v[i].x + v[i].y + v[i].z + v[i].w; }
    s = wred(s);
    const float mean = s * (1.f / CC);
    float q = 0.f;
#pragma unroll
    for (int i = 0; i < 4; ++i) {
        float a = v[i].x - mean, b2 = v[i].y - mean, c = v[i].z - mean, d = v[i].w - mean;
        q += a * a + b2 * b2 + c * c + d * d;
    }
    q = wred(q);
    const float rs = rsqrtf(q * (1.f / CC) + 1e-5f);
    const float4* g4 = (const float4*)g;
    const float4* b4 = (const float4*)bta;
    float4* nm = nullptr;
    if (rr >= K - MM) nm = (float4*)(nmOut + ((size_t)b * MM + (rr - (K - MM))) * CC);
#pragma unroll
    for (int i = 0; i < 4; ++i) {
        float4 gg = g4[i * 64 + lane], bb = b4[i * 64 + lane];
        float4 o;
        o.x = (v[i].x - mean) * rs * gg.x + bb.x;
        o.y = (v[i].y - mean) * rs * gg.y + bb.y;
        o.z = (v[i].z - mean) * rs * gg.z + bb.z;
        o.w = (v[i].w - mean) * rs * gg.w + bb.w;
        union { f16 h4[4]; uint2 u; } pk;
        pk.h4[0] = (f16)o.x; pk.h4[1] = (f16)o.y; pk.h4[2] = (f16)o.z; pk.h4[3] = (f16)o.w;
        crow[i * 64 + lane] = pk.u;
        if (nm) nm[i * 64 + lane] = o;
    }
}

// ---------------- 128x128 f16 MFMA GEMM: BK=32 2-slot, 32KB LDS -> 3 blocks/CU (TLP) ----------------
// EPI: 0 plain f32, 1 +bias f32, 2 +bias+gelu f16, 3 +bias+res f32, 4 +bias f16
template <int EPI>
__global__ __launch_bounds__(256, 3)
void gemm_k(const f16* __restrict__ A, const f16* __restrict__ BT,
            const float* __restrict__ bias, const float* __restrict__ res,
            float* __restrict__ outF, f16* __restrict__ outH,
            int M, int N, int Kc)
{
    __shared__ f16 sA[2][128 * 32];
    __shared__ f16 sB[2][128 * 32];

    const int nbn = N >> 7;
    const int nwg = gridDim.x;
    const int id = blockIdx.x;
    const int qq = nwg >> 3, r8 = nwg & 7;
    const int xcd = id & 7, pos = id >> 3;
    const int wgid = (xcd < r8 ? xcd * (qq + 1) : r8 * (qq + 1) + (xcd - r8) * qq) + pos;
    const int bm = wgid / nbn, bn = wgid % nbn;

    const int tid = threadIdx.x;
    const int w = tid >> 6, l = tid & 63;
    const int wr = w >> 1, wc = w & 1;
    const int lr = l & 15, lk = (l >> 4) * 8;

    f32x4 acc[4][4] = {};

    const int ar = w * 32 + (l >> 2);      // staging row (inst0); inst1 adds 16
    const int ak = (l & 3) * 8;
    const f16* gA = A + (size_t)(bm * 128 + ar) * Kc + ak;
    const f16* gB = BT + (size_t)(bn * 128 + ar) * Kc + ak;

    auto stage = [&](int slot, int kt) {
        g2lds16(gA + kt, &sA[slot][w * 1024]);
        g2lds16(gA + kt + (size_t)16 * Kc, &sA[slot][w * 1024 + 512]);
        g2lds16(gB + kt, &sB[slot][w * 1024]);
        g2lds16(gB + kt + (size_t)16 * Kc, &sB[slot][w * 1024 + 512]);
    };

    // prologue
    stage(0, 0);
    asm volatile("s_waitcnt vmcnt(0)" ::: "memory");
    __builtin_amdgcn_s_barrier();

    int cur = 0;
    for (int kt = 0; kt < Kc; kt += 32) {
        if (kt + 32 < Kc) stage(cur ^ 1, kt + 32);   // issue next-tile loads FIRST
        f16x8 af[4], bf[4];
#pragma unroll
        for (int mi = 0; mi < 4; ++mi) af[mi] = *(const f16x8*)&sA[cur][(wr * 64 + mi * 16 + lr) * 32 + lk];
#pragma unroll
        for (int ni = 0; ni < 4; ++ni) bf[ni] = *(const f16x8*)&sB[cur][(wc * 64 + ni * 16 + lr) * 32 + lk];
        asm volatile("s_waitcnt lgkmcnt(0)" ::: "memory");
        __builtin_amdgcn_sched_barrier(0);
#pragma unroll
        for (int mi = 0; mi < 4; ++mi)
#pragma unroll
            for (int ni = 0; ni < 4; ++ni)
                acc[mi][ni] = __builtin_amdgcn_mfma_f32_16x16x32_f16(af[mi], bf[ni], acc[mi][ni], 0, 0, 0);
        asm volatile("s_waitcnt vmcnt(0)" ::: "memory");
        __builtin_amdgcn_s_barrier();
        cur ^= 1;
    }

    const int orow0 = bm * 128 + wr * 64 + (l >> 4) * 4;
    const int ocol0 = bn * 128 + wc * 64 + lr;
#pragma unroll
    for (int mi = 0; mi < 4; ++mi)
#pragma unroll
        for (int ni = 0; ni < 4; ++ni) {
            const int col = ocol0 + ni * 16;
            const float bv = (EPI >= 1) ? bias[col] : 0.f;
#pragma unroll
            for (int r = 0; r < 4; ++r) {
                const int row = orow0 + mi * 16 + r;
                float v = acc[mi][ni][r] + bv;
                if (EPI == 2) {
                    const float u = 1.5957691216057308f * (v + 0.044715f * v * v * v);
                    const float e = __expf(u);
                    v = v * e / (e + 1.f);           // 0.5*v*(1+tanh(u/2))
                    outH[(size_t)row * N + col] = (f16)v;
                } else if (EPI == 4) {
                    outH[(size_t)row * N + col] = (f16)v;
                } else if (EPI == 3) {
                    v += res[(size_t)row * N + col];
                    outF[(size_t)row * N + col] = v;
                } else {
                    outF[(size_t)row * N + col] = v;
                }
            }
        }
}

// ---------------- 128x64 f16 MFMA GEMM (proj/fc2): 24KB LDS, 3 blocks/CU ----------------
template <int EPI>
__global__ __launch_bounds__(256, 3)
void gemm64_k(const f16* __restrict__ A, const f16* __restrict__ BT,
              const float* __restrict__ bias, const float* __restrict__ res,
              float* __restrict__ outF, f16* __restrict__ outH,
              int M, int N, int Kc)
{
    __shared__ f16 sA[2][128 * 32];
    __shared__ f16 sB[2][64 * 32];

    const int nbn = N >> 6;
    const int nwg = gridDim.x;
    const int id = blockIdx.x;
    const int qq = nwg >> 3, r8 = nwg & 7;
    const int xcd = id & 7, pos = id >> 3;
    const int wgid = (xcd < r8 ? xcd * (qq + 1) : r8 * (qq + 1) + (xcd - r8) * qq) + pos;
    const int bm = wgid / nbn, bn = wgid % nbn;

    const int tid = threadIdx.x;
    const int w = tid >> 6, l = tid & 63;
    const int wr = w >> 1, wc = w & 1;
    const int lr = l & 15, lk = (l >> 4) * 8;

    f32x4 acc[4][2] = {};

    const int ar = w * 32 + (l >> 2);      // A staging row (inst0); inst1 adds 16
    const int br = w * 16 + (l >> 2);      // B staging row
    const int ak = (l & 3) * 8;
    const f16* gA = A + (size_t)(bm * 128 + ar) * Kc + ak;
    const f16* gB = BT + (size_t)(bn * 64 + br) * Kc + ak;

    auto stage = [&](int slot, int kt) {
        g2lds16(gA + kt, &sA[slot][w * 1024]);
        g2lds16(gA + kt + (size_t)16 * Kc, &sA[slot][w * 1024 + 512]);
        g2lds16(gB + kt, &sB[slot][w * 512]);
    };

    // prologue
    stage(0, 0);
    asm volatile("s_waitcnt vmcnt(0)" ::: "memory");
    __builtin_amdgcn_s_barrier();

    int cur = 0;
    for (int kt = 0; kt < Kc; kt += 32) {
        if (kt + 32 < Kc) stage(cur ^ 1, kt + 32);   // issue next-tile loads FIRST
        f16x8 af[4], bf[2];
#pragma unroll
        for (int mi = 0; mi < 4; ++mi) af[mi] = *(const f16x8*)&sA[cur][(wr * 64 + mi * 16 + lr) * 32 + lk];
#pragma unroll
        for (int ni = 0; ni < 2; ++ni) bf[ni] = *(const f16x8*)&sB[cur][(wc * 32 + ni * 16 + lr) * 32 + lk];
        asm volatile("s_waitcnt lgkmcnt(0)" ::: "memory");
        __builtin_amdgcn_sched_barrier(0);
#pragma unroll
        for (int mi = 0; mi < 4; ++mi)
#pragma unroll
            for (int ni = 0; ni < 2; ++ni)
                acc[mi][ni] = __builtin_amdgcn_mfma_f32_16x16x32_f16(af[mi], bf[ni], acc[mi][ni], 0, 0, 0);
        asm volatile("s_waitcnt vmcnt(0)" ::: "memory");
        __builtin_amdgcn_s_barrier();
        cur ^= 1;
    }

    const int orow0 = bm * 128 + wr * 64 + (l >> 4) * 4;
    const int ocol0 = bn * 64 + wc * 32 + lr;
#pragma unroll
    for (int mi = 0; mi < 4; ++mi)
#pragma unroll
        for (int ni = 0; ni < 2; ++ni) {
            const int col = ocol0 + ni * 16;
            const float bv = (EPI >= 1) ? bias[col] : 0.f;
#pragma unroll
            for (int r = 0; r < 4; ++r) {
                const int row = orow0 + mi * 16 + r;
                float v = acc[mi][ni][r] + bv;
                if (EPI == 3) {
                    v += res[(size_t)row * N + col];
                    outF[(size_t)row * N + col] = v;
                } else if (EPI == 4) {
                    outH[(size_t)row * N + col] = (f16)v;
                } else {
                    outF[(size_t)row * N + col] = v;
                }
            }
        }
}

// ---------------- 256x256 8-phase f16 MFMA GEMM (HK-style schedule), lm_head ----------------
template <int EPI>
__global__ __launch_bounds__(512, 2)
void gemm256_k(const f16* __restrict__ A, const f16* __restrict__ BT,
               const float* __restrict__ bias,
               float* __restrict__ outF, f16* __restrict__ outH,
               int M, int N, int Kc)
{
    __shared__ char ldsbuf[131072];
    char* ldsA = ldsbuf;
    char* ldsB = ldsbuf + 65536;

    // bijective XCD swizzle (m204), bm-fastest for B-panel L2 reuse
    const int nbm = M >> 8;
    const int nwg = gridDim.x;
    int id = blockIdx.x;
    const int qq = nwg >> 3, rr8 = nwg & 7;
    const int xcd = id & 7, pos = id >> 3;
    const int wgid = (xcd < rr8 ? xcd * (qq + 1) : rr8 * (qq + 1) + (xcd - rr8) * qq) + pos;
    const int bm = wgid % nbm, bn = wgid / nbm;

    const int t_ = threadIdx.x;
    const int w = t_ >> 6, l = t_ & 63;
    const int wm = w >> 2, wn = w & 3;
    const int lr = l & 15, lhi = l >> 4;

    const f16* gA = A + (size_t)bm * 256 * Kc;
    const f16* gB = BT + (size_t)bn * 256 * Kc;

    auto stage = [&](const f16* Gbase, char* ldsHalf, int kt) {
#pragma unroll
        for (int ii = 0; ii < 2; ++ii) {
            const int gb = (w << 1) + ii;
            const int s = (gb << 6) + l;
            const int row = s >> 3, grp = s & 7;
            g2lds16(Gbase + (size_t)row * Kc + kt + ((grp ^ (row & 7)) << 3),
                    ldsHalf + gb * 1024);
        }
    };
    auto rdfrag = [&](const char* halfBase, int rowInHalf, int ks) -> f16x8 {
        return *(const f16x8*)(halfBase + rowInHalf * 128 +
                               ((((ks << 2) + lhi) ^ (rowInHalf & 7)) << 4));
    };

    f32x4 acc[8][4] = {};
    f16x8 aA[4][2], blo[2][2], bhi[2][2];

    const int NT = Kc >> 6;
    const char* aHalf0 = ldsA + wm * 16384;
    const char* aHalf1 = ldsA + 32768 + wm * 16384;
    const char* bHalf0 = ldsB + (wn >> 1) * 16384;
    const char* bHalf1 = ldsB + 32768 + (wn >> 1) * 16384;
    const int brow = (wn & 1) * 64;

    // ---- prologue: T0 full + T1 B-halves, drain, publish ----
    stage(gA, ldsA + 0, 0);
    stage(gA + (size_t)128 * Kc, ldsA + 16384, 0);
    stage(gB, ldsB + 0, 0);
    stage(gB + (size_t)128 * Kc, ldsB + 16384, 0);
    stage(gB, ldsB + 32768, 64);
    stage(gB + (size_t)128 * Kc, ldsB + 49152, 64);
    asm volatile("s_waitcnt vmcnt(0)" ::: "memory");
    __builtin_amdgcn_s_barrier();

#define MFMA_QUAD(MQ, NQ, BR)                                                            \
    __builtin_amdgcn_s_setprio(1);                                                       \
    _Pragma("unroll") for (int mf = 0; mf < 4; ++mf)                                     \
    _Pragma("unroll") for (int nf = 0; nf < 2; ++nf)                                     \
    _Pragma("unroll") for (int ks = 0; ks < 2; ++ks)                                     \
        acc[(MQ)*4 + mf][(NQ)*2 + nf] =                                                  \
            __builtin_amdgcn_mfma_f32_16x16x32_f16(aA[mf][ks], BR[nf][ks],               \
                                                   acc[(MQ)*4 + mf][(NQ)*2 + nf], 0, 0, 0); \
    __builtin_amdgcn_s_setprio(0);

#define PHASE_SYNC()                                          \
    __builtin_amdgcn_s_barrier();                             \
    asm volatile("s_waitcnt lgkmcnt(0)" ::: "memory");        \
    __builtin_amdgcn_sched_barrier(0);

    for (int t = 0; t < NT; t += 2) {
        const bool pf0 = (t + 2) < NT;
        const int kb = (t + 1) << 6, kc2 = (t + 2) << 6, kd = (t + 3) << 6;

        // ---- PH1 ----
#pragma unroll
        for (int mf = 0; mf < 4; ++mf)
#pragma unroll
            for (int ks = 0; ks < 2; ++ks) aA[mf][ks] = rdfrag(aHalf0, mf * 16 + lr, ks);
#pragma unroll
        for (int nf = 0; nf < 2; ++nf)
#pragma unroll
            for (int ks = 0; ks < 2; ++ks) blo[nf][ks] = rdfrag(bHalf0, brow + nf * 16 + lr, ks);
        stage(gA, ldsA + 32768, kb);
        PHASE_SYNC();
        MFMA_QUAD(0, 0, blo);
        __builtin_amdgcn_s_barrier();

        // ---- PH2 ----
#pragma unroll
        for (int nf = 0; nf < 2; ++nf)
#pragma unroll
            for (int ks = 0; ks < 2; ++ks) bhi[nf][ks] = rdfrag(bHalf0, brow + 32 + nf * 16 + lr, ks);
        stage(gA + (size_t)128 * Kc, ldsA + 49152, kb);
        PHASE_SYNC();
        MFMA_QUAD(0, 1, bhi);
        __builtin_amdgcn_s_barrier();

        // ---- PH3 ----
#pragma unroll
        for (int mf = 0; mf < 4; ++mf)
#pragma unroll
            for (int ks = 0; ks < 2; ++ks) aA[mf][ks] = rdfrag(aHalf0, 64 + mf * 16 + lr, ks);
        if (pf0) stage(gB, ldsB + 0, kc2);
        PHASE_SYNC();
        MFMA_QUAD(1, 0, blo);
        __builtin_amdgcn_s_barrier();

        // ---- PH4 ----
        if (pf0) {
            stage(gB + (size_t)128 * Kc, ldsB + 16384, kc2);
            asm volatile("s_waitcnt vmcnt(4)" ::: "memory");
        } else {
            asm volatile("s_waitcnt vmcnt(0)" ::: "memory");
        }
        PHASE_SYNC();
        MFMA_QUAD(1, 1, bhi);
        __builtin_amdgcn_s_barrier();

        // ---- PH5 ----
#pragma unroll
        for (int mf = 0; mf < 4; ++mf)
#pragma unroll
            for (int ks = 0; ks < 2; ++ks) aA[mf][ks] = rdfrag(aHalf1, mf * 16 + lr, ks);
#pragma unroll
        for (int nf = 0; nf < 2; ++nf)
#pragma unroll
            for (int ks = 0; ks < 2; ++ks) blo[nf][ks] = rdfrag(bHalf1, brow + nf * 16 + lr, ks);
        if (pf0) stage(gA, ldsA + 0, kc2);
        PHASE_SYNC();
        MFMA_QUAD(0, 0, blo);
        __builtin_amdgcn_s_barrier();

        // ---- PH6 ----
#pragma unroll
        for (int nf = 0; nf < 2; ++nf)
#pragma unroll
            for (int ks = 0; ks < 2; ++ks) bhi[nf][ks] = rdfrag(bHalf1, brow + 32 + nf * 16 + lr, ks);
        if (pf0) stage(gA + (size_t)128 * Kc, ldsA + 16384, kc2);
        PHASE_SYNC();
        MFMA_QUAD(0, 1, bhi);
        __builtin_amdgcn_s_barrier();

        // ---- PH7 ----
#pragma unroll
        for (int mf = 0; mf < 4; ++mf)
#pragma unroll
            for (int ks = 0; ks < 2; ++ks) aA[mf][ks] = rdfrag(aHalf1, 64 + mf * 16 + lr, ks);
        if (pf0) stage(gB, ldsB + 32768, kd);
        PHASE_SYNC();
        MFMA_QUAD(1, 0, blo);
        __builtin_amdgcn_s_barrier();

        // ---- PH8 ----
        if (pf0) {
            stage(gB + (size_t)128 * Kc, ldsB + 49152, kd);
            asm volatile("s_waitcnt vmcnt(4)" ::: "memory");
        } else {
            asm volatile("s_waitcnt vmcnt(0)" ::: "memory");
        }
        PHASE_SYNC();
        MFMA_QUAD(1, 1, bhi);
        __builtin_amdgcn_s_barrier();
    }
#undef MFMA_QUAD
#undef PHASE_SYNC

    // ---- epilogue (direct stores) ----
    const int rb0 = bm * 256 + wm * 128 + lhi * 4;
    const int cb0 = bn * 256 + wn * 64 + lr;
#pragma unroll
    for (int mf = 0; mf < 8; ++mf)
#pragma unroll
        for (int nf = 0; nf < 4; ++nf) {
            const int col = cb0 + nf * 16;
            const float bv = (EPI >= 1) ? bias[col] : 0.f;
#pragma unroll
            for (int r = 0; r < 4; ++r) {
                const int row = rb0 + mf * 16 + r;
                float v = acc[mf][nf][r] + bv;
                if (EPI == 4) {
                    outH[(size_t)row * N + col] = (f16)v;
                } else {
                    outF[(size_t)row * N + col] = v;
                }
            }
        }
}

// ---------------- attention: QBLK=128 MFMA flash, defer-max (exp2 domain), dbuf K/Vt ----------------
// 4 waves x 32 q-rows (2 row-groups of 16); kf/vb fragments shared across row-groups.
__global__ __launch_bounds__(256)
void attn_k(const f16* __restrict__ qkv, const float* __restrict__ remb,
            const float* __restrict__ rbias, f16* __restrict__ yH, int K)
{
    __shared__ f16 K_lds[2][64 * 64];   // [slot][krow][d], 16B-granule XOR swizzle by (krow&7)
    __shared__ f16 Vt_lds[2][64 * 64];  // [slot][d][k],    XOR swizzle by (d&7)
    __shared__ f16 P_lds[128 * 64];     // [q][k], wave-private strips, XOR swizzle by (q&7)
    __shared__ float s_s[132];

    const int b = blockIdx.x >> 4, h = blockIdx.x & 15;
    const int i0 = blockIdx.y * 128;
    const int t = threadIdx.x;
    const int w = t >> 6, l = t & 63;
    const int c = l & 15, g = l >> 4;

    const f16* qg = qkv + (size_t)b * K * 3072 + h * 64;
    const f16* kg = qg + 1024;
    const f16* vg = qg + 2048;
    const float* rb = rbias + h * 64;
    const float* re = remb + h * 64;

    const int kb = t >> 4, db = t & 15;  // V staging coords

    const float SCL = 0.125f * 1.44269504088896f;   // log2 domain softmax

    auto stageK = [&](int j0, int slot) {
#pragma unroll
        for (int i = 0; i < 2; ++i) {
            const int s = w * 128 + i * 64 + l;
            const int row = s >> 3, grp = s & 7;
            g2lds16(kg + (size_t)(j0 + row) * 3072 + ((grp ^ (row & 7)) * 8),
                    (char*)K_lds[slot] + (size_t)(w * 128 + i * 64) * 16);
        }
    };
    auto loadV = [&](int j0, uint2* rowv) {
#pragma unroll
        for (int i = 0; i < 4; ++i)
            rowv[i] = *(const uint2*)(vg + (size_t)(j0 + kb * 4 + i) * 3072 + db * 4);
    };
    auto writeVt = [&](const uint2* rowvu, int slot) {
#pragma unroll
        for (int j = 0; j < 4; ++j) {
            union { uint2 u; f16 hh[4]; } colv;
#pragma unroll
            for (int i = 0; i < 4; ++i) {
                union { uint2 u; f16 hh[4]; } rv; rv.u = rowvu[i];
                colv.hh[i] = rv.hh[j];
            }
            const int d = db * 4 + j;
            *(uint2*)((char*)Vt_lds[slot] + d * 128 + ((kb * 8) ^ ((d & 7) << 4))) = colv.u;
        }
    };

    // q fragments (+rbias): rows w*32 + rg*16 + c
    f16x8 qf[2][2];
#pragma unroll
    for (int rg = 0; rg < 2; ++rg) {
        const int qrow = i0 + w * 32 + rg * 16 + c;
#pragma unroll
        for (int ks = 0; ks < 2; ++ks) {
            f16x8 raw = *(const f16x8*)(qg + (size_t)qrow * 3072 + ks * 32 + g * 8);
            f16x8 o;
#pragma unroll
            for (int j = 0; j < 8; ++j) o[j] = (f16)((float)raw[j] + rb[ks * 32 + g * 8 + j]);
            qf[rg][ks] = o;
        }
    }
    // s_i = (q_i + rbias).remb for i in [i0, i0+128]
    if (t < 130) {
        float sv = 0.f;
        const int i = i0 + t;
        if (i < K) {
            const f16* qr = qg + (size_t)i * 3072;
#pragma unroll
            for (int d8 = 0; d8 < 8; ++d8) {
                f16x8 v8 = *(const f16x8*)(qr + d8 * 8);
#pragma unroll
                for (int j = 0; j < 8; ++j) sv += ((float)v8[j] + rb[d8 * 8 + j]) * re[d8 * 8 + j];
            }
        }
        s_s[t] = sv;
    }

    // ---- prologue: stage tile 0 into slot 0 ----
    {
        uint2 rowv[4];
        stageK(0, 0);
        loadV(0, rowv);
        writeVt(rowv, 0);
    }
    __syncthreads();

    float sA[2][4], sB[2][4];
#pragma unroll
    for (int rg = 0; rg < 2; ++rg)
#pragma unroll
        for (int r = 0; r < 4; ++r) {
            sA[rg][r] = s_s[w * 32 + rg * 16 + g * 4 + r];
            sB[rg][r] = s_s[w * 32 + rg * 16 + g * 4 + r + 1];
        }

    float m_run[2][4] = {};
    float psum[2][4] = {};
    f32x4 yacc[2][4] = {};

    int cur = 0;
    for (int j0 = 0; j0 < K; j0 += 64, cur ^= 1) {
        const bool more = (j0 + 64) < K;
        uint2 rowv[4];
        if (more) { stageK(j0 + 64, cur ^ 1); loadV(j0 + 64, rowv); }

        // ---- QK^T: kf read once, used by both row-groups ----
        f32x4 sc[2][4] = {};
#pragma unroll
        for (int tt = 0; tt < 4; ++tt) {
            const int row = tt * 16 + c;
#pragma unroll
            for (int ks = 0; ks < 2; ++ks) {
                f16x8 kf = *(const f16x8*)((char*)K_lds[cur] + row * 128 + ((ks * 64 + g * 16) ^ ((row & 7) << 4)));
#pragma unroll
                for (int rg = 0; rg < 2; ++rg)
                    sc[rg][tt] = __builtin_amdgcn_mfma_f32_16x16x32_f16(qf[rg][ks], kf, sc[rg][tt], 0, 0, 0);
            }
        }

        // ---- BD + scale (log2 domain) ----
        float p[2][4][4];
#pragma unroll
        for (int rg = 0; rg < 2; ++rg)
#pragma unroll
            for (int tt = 0; tt < 4; ++tt)
#pragma unroll
                for (int r = 0; r < 4; ++r) {
                    const int gi = i0 + w * 32 + rg * 16 + g * 4 + r;
                    const int gj = j0 + tt * 16 + c;
                    const float bd = (gj <= gi) ? sA[rg][r] : ((gj == gi + 1) ? 0.f : sB[rg][r]);
                    p[rg][tt][r] = (sc[rg][tt][r] + bd) * SCL;
                }

        // ---- defer-max: fast path has NO cross-lane ops ----
        float lmax[2][4];
        bool need = false;
#pragma unroll
        for (int rg = 0; rg < 2; ++rg)
#pragma unroll
            for (int r = 0; r < 4; ++r) {
                lmax[rg][r] = fmaxf(fmaxf(p[rg][0][r], p[rg][1][r]), fmaxf(p[rg][2][r], p[rg][3][r]));
                need |= (lmax[rg][r] > m_run[rg][r] + 8.f);
            }
        if (__any(need)) {
#pragma unroll
            for (int rg = 0; rg < 2; ++rg)
#pragma unroll
                for (int r = 0; r < 4; ++r) {
                    float mx = lmax[rg][r];
                    mx = fmaxf(mx, __shfl_xor(mx, 1));
                    mx = fmaxf(mx, __shfl_xor(mx, 2));
                    mx = fmaxf(mx, __shfl_xor(mx, 4));
                    mx = fmaxf(mx, __shfl_xor(mx, 8));
                    if (mx > m_run[rg][r]) {
                        const float f = exp2f(m_run[rg][r] - mx);
                        m_run[rg][r] = mx;
                        psum[rg][r] *= f;
#pragma unroll
                        for (int tt = 0; tt < 4; ++tt) yacc[rg][tt][r] *= f;
                    }
                }
        }
#pragma unroll
        for (int rg = 0; rg < 2; ++rg)
#pragma unroll
            for (int r = 0; r < 4; ++r) {
                float ss = 0.f;
#pragma unroll
                for (int tt = 0; tt < 4; ++tt) {
                    const float e = exp2f(p[rg][tt][r] - m_run[rg][r]);
                    p[rg][tt][r] = e;
                    ss += e;
                }
                psum[rg][r] += ss;
            }

        // ---- write next Vt, then P (wave-private strips) ----
        if (more) writeVt(rowv, cur ^ 1);
#pragma unroll
        for (int rg = 0; rg < 2; ++rg)
#pragma unroll
            for (int tt = 0; tt < 4; ++tt)
#pragma unroll
                for (int r = 0; r < 4; ++r) {
                    const int q = w * 32 + rg * 16 + g * 4 + r;
                    *(f16*)((char*)P_lds + q * 128 + (((tt * 16 + c) * 2) ^ ((q & 7) << 4))) = (f16)p[rg][tt][r];
                }
        asm volatile("s_waitcnt lgkmcnt(0)" ::: "memory");
        __builtin_amdgcn_sched_barrier(0);

        // ---- PV: vb read once, used by both row-groups ----
        {
            f16x8 pa[2][2];
#pragma unroll
            for (int rg = 0; rg < 2; ++rg) {
                const int qrow = w * 32 + rg * 16 + c;
#pragma unroll
                for (int ks = 0; ks < 2; ++ks)
                    pa[rg][ks] = *(const f16x8*)((char*)P_lds + qrow * 128 + ((ks * 64 + g * 16) ^ ((qrow & 7) << 4)));
            }
#pragma unroll
            for (int tt = 0; tt < 4; ++tt) {
                const int drow = tt * 16 + c;
#pragma unroll
                for (int ks = 0; ks < 2; ++ks) {
                    f16x8 vb = *(const f16x8*)((char*)Vt_lds[cur] + drow * 128 + ((ks * 64 + g * 16) ^ ((drow & 7) << 4)));
#pragma unroll
                    for (int rg = 0; rg < 2; ++rg)
                        yacc[rg][tt] = __builtin_amdgcn_mfma_f32_16x16x32_f16(pa[rg][ks], vb, yacc[rg][tt], 0, 0, 0);
                }
            }
        }
        __syncthreads();
    }

    // ---- final row-sum reduce + normalize + store ----
#pragma unroll
    for (int rg = 0; rg < 2; ++rg)
#pragma unroll
        for (int r = 0; r < 4; ++r) {
            float ps = psum[rg][r];
            ps += __shfl_xor(ps, 1);
            ps += __shfl_xor(ps, 2);
            ps += __shfl_xor(ps, 4);
            ps += __shfl_xor(ps, 8);
            const float inv = 1.f / ps;
            const int row = i0 + w * 32 + rg * 16 + g * 4 + r;
            f16* dst = yH + (size_t)(b * K + row) * CC + h * 64;
#pragma unroll
            for (int tt = 0; tt < 4; ++tt)
                dst[tt * 16 + c] = (f16)(yacc[rg][tt][r] * inv);
        }
}

// ---------------- host ----------------
extern "C" void kernel_launch(void* const* d_in, const int* in_sizes, int n_in,
                              void* d_out, int out_size, void* d_ws, size_t ws_size,
                              hipStream_t stream)
{
    (void)in_sizes; (void)n_in; (void)out_size; (void)ws_size;
    const int*   idx    = (const int*)  d_in[0];
    const float* mems   = (const float*)d_in[1];
    const float* wte    = (const float*)d_in[2];
    const float* ln1_g  = (const float*)d_in[3];
    const float* ln1_b  = (const float*)d_in[4];
    const float* attn_w = (const float*)d_in[5];
    const float* attn_b = (const float*)d_in[6];
    const float* proj_w = (const float*)d_in[7];
    const float* proj_b = (const float*)d_in[8];
    const float* r_emb  = (const float*)d_in[9];
    const float* r_bias = (const float*)d_in[10];
    const float* ln2_g  = (const float*)d_in[11];
    const float* ln2_b  = (const float*)d_in[12];
    const float* fc_w   = (const float*)d_in[13];
    const float* fc_b   = (const float*)d_in[14];
    const float* fc2_w  = (const float*)d_in[15];
    const float* fc2_b  = (const float*)d_in[16];
    const float* lnf_g  = (const float*)d_in[17];
    const float* lnf_b  = (const float*)d_in[18];
    const float* lm_w   = (const float*)d_in[19];
    float* out = (float*)d_out;

    char* wp = (char*)d_ws; size_t off = 0;
    auto carve = [&](size_t bytes) -> void* {
        void* p = wp + off; off += (bytes + 255) & ~(size_t)255; return p;
    };
    const int KMAX = TT + LNUM * MM;  // 1792
    f16*  attn_wT = (f16*) carve((size_t)LNUM * 3 * CC * CC * 2);
    f16*  proj_wT = (f16*) carve((size_t)LNUM * CC * CC * 2);
    f16*  fc_wT   = (f16*) carve((size_t)LNUM * 4 * CC * CC * 2);
    f16*  fc2_wT  = (f16*) carve((size_t)LNUM * 4 * CC * CC * 2);
    f16*  lm_wT   = (f16*) carve((size_t)VV * CC * 2);
    float* x0     = (float*)carve((size_t)BB * KMAX * CC * 4);
    float* x1     = (float*)carve((size_t)BB * KMAX * CC * 4);
    f16*  catH    = (f16*) carve((size_t)BB * KMAX * CC * 2);
    f16*  qkv16   = (f16*) carve((size_t)BB * KMAX * 3 * CC * 2);
    f16*  yH      = (f16*) carve((size_t)BB * KMAX * CC * 2);
    float* yp     = (float*)carve((size_t)BB * KMAX * CC * 4);
    f16*  h2H     = (f16*) carve((size_t)BB * KMAX * CC * 2);
    f16*  a1H     = (f16*) carve((size_t)BB * KMAX * 4 * CC * 2);
    f16*  xfH     = (f16*) carve((size_t)BB * KMAX * CC * 2);

    // weight transposes (f32 -> f16, (R,Cc) -> (Cc,R)), 64x64 tiles
    transpose_k<<<dim3(3 * CC / 64, CC / 64, LNUM), 256, 0, stream>>>(attn_w, attn_wT, CC, 3 * CC);
    transpose_k<<<dim3(CC / 64, CC / 64, LNUM),     256, 0, stream>>>(proj_w, proj_wT, CC, CC);
    transpose_k<<<dim3(4 * CC / 64, CC / 64, LNUM), 256, 0, stream>>>(fc_w, fc_wT, CC, 4 * CC);
    transpose_k<<<dim3(CC / 64, 4 * CC / 64, LNUM), 256, 0, stream>>>(fc2_w, fc2_wT, 4 * CC, CC);
    transpose_k<<<dim3(VV / 64, CC / 64, 1),        256, 0, stream>>>(lm_w, lm_wT, CC, VV);

    embed_k<<<BB * TT, 256, 0, stream>>>(idx, wte, x0);

    const size_t LOGITS = (size_t)BB * KMAX * VV;
    float* xcur = x0; float* xnxt = x1;
    for (int l = 0; l < LNUM; ++l) {
        const int Kin = TT + MM * l;
        const int K = Kin + MM;
        const int Mrows = BB * K;
        const int nbm128 = Mrows / 128;
        ln1cat_k<<<Mrows / 4, 256, 0, stream>>>(xcur, mems + (size_t)l * BB * MM * CC,
                                                ln1_g + l * CC, ln1_b + l * CC,
                                                catH, out + LOGITS + (size_t)l * BB * MM * CC, K, Kin);
        gemm_k<4><<<(3 * CC / 128) * nbm128, 256, 0, stream>>>(
            catH, attn_wT + (size_t)l * 3 * CC * CC, attn_b + (size_t)l * 3 * CC, nullptr,
            nullptr, qkv16, Mrows, 3 * CC, CC);
        attn_k<<<dim3(BB * HH, K / 128), 256, 0, stream>>>(
            qkv16, r_emb + (size_t)l * HH * DHH, r_bias + (size_t)l * HH * DHH, yH, K);
        gemm64_k<1><<<(CC / 64) * nbm128, 256, 0, stream>>>(
            yH, proj_wT + (size_t)l * CC * CC, proj_b + (size_t)l * CC, nullptr,
            yp, nullptr, Mrows, CC, CC);
        ln_k<<<Mrows / 4, 256, 0, stream>>>(yp, ln2_g + l * CC, ln2_b + l * CC, h2H);
        gemm_k<2><<<(4 * CC / 128) * nbm128, 256, 0, stream>>>(
            h2H, fc_wT + (size_t)l * 4 * CC * CC, fc_b + (size_t)l * 4 * CC, nullptr,
            nullptr, a1H, Mrows, 4 * CC, CC);
        gemm64_k<3><<<(CC / 64) * nbm128, 256, 0, stream>>>(
            a1H, fc2_wT + (size_t)l * 4 * CC * CC, fc2_b + (size_t)l * CC, yp,
            xnxt, nullptr, Mrows, CC, 4 * CC);
        float* tmp = xcur; xcur = xnxt; xnxt = tmp;
    }
    ln_k<<<(BB * KMAX) / 4, 256, 0, stream>>>(xcur, lnf_g, lnf_b, xfH);
    gemm256_k<0><<<(BB * KMAX / 256) * (VV / 256), 512, 0, stream>>>(
        xfH, lm_wT, nullptr, out, nullptr, BB * KMAX, VV, CC);
}

// Round 14
// 1886.767 us; speedup vs baseline: 1.1075x; 1.1075x over previous
//
#include <hip/hip_runtime.h>
#include <hip/hip_bf16.h>
#include <hip/hip_fp16.h>

#define LNUM 6
#define BB 2
#define TT 1024
#define CC 1024
#define HH 16
#define DHH 64
#define VV 32000
#define MM 128

typedef _Float16 f16;
typedef _Float16 f16x8 __attribute__((ext_vector_type(8)));
typedef float f32x4 __attribute__((ext_vector_type(4)));

__device__ __forceinline__ void g2lds16(const void* g, void* l) {
    __builtin_amdgcn_global_load_lds((const __attribute__((address_space(1))) void*)g,
                                     (__attribute__((address_space(3))) void*)l,
                                     16, 0, 0);
}

__device__ __forceinline__ float wred(float v) {
#pragma unroll
    for (int o = 32; o > 0; o >>= 1) v += __shfl_xor(v, o);
    return v;
}

// ---------------- weight transpose + f32->f16 convert: W (R,Cc) -> WT (Cc,R) ----------------
__global__ __launch_bounds__(256)
void transpose_k(const float* __restrict__ W, f16* __restrict__ WT, int R, int Cc)
{
    __shared__ float tile[64][65];
    const size_t base = (size_t)blockIdx.z * R * Cc;
    const int c0 = blockIdx.x * 64, r0 = blockIdx.y * 64;
    const int tx = threadIdx.x & 15, ty = threadIdx.x >> 4;  // 16 x 16
#pragma unroll
    for (int i = 0; i < 4; ++i) {
        const int row = ty + i * 16;
        float4 v = *(const float4*)&W[base + (size_t)(r0 + row) * Cc + c0 + tx * 4];
        tile[row][tx * 4 + 0] = v.x;
        tile[row][tx * 4 + 1] = v.y;
        tile[row][tx * 4 + 2] = v.z;
        tile[row][tx * 4 + 3] = v.w;
    }
    __syncthreads();
#pragma unroll
    for (int i = 0; i < 4; ++i) {
        const int c = ty + i * 16;
        union { f16 h4[4]; uint2 u; } pk;
        pk.h4[0] = (f16)tile[tx * 4 + 0][c];
        pk.h4[1] = (f16)tile[tx * 4 + 1][c];
        pk.h4[2] = (f16)tile[tx * 4 + 2][c];
        pk.h4[3] = (f16)tile[tx * 4 + 3][c];
        *(uint2*)&WT[base + (size_t)(c0 + c) * R + r0 + tx * 4] = pk.u;
    }
}

// ---------------- embedding gather ----------------
__global__ __launch_bounds__(256)
void embed_k(const int* __restrict__ idx, const float* __restrict__ wte, float* __restrict__ X)
{
    const int row = blockIdx.x;            // B*T rows
    const int id = idx[row];
    const float4* src = (const float4*)(wte + (size_t)id * CC);
    float4* dst = (float4*)(X + (size_t)row * CC);
    dst[threadIdx.x] = src[threadIdx.x];
}

// ---------------- LN (generic, f16 out): one wave per row of C=1024 ----------------
__global__ __launch_bounds__(256)
void ln_k(const float* __restrict__ X, const float* __restrict__ g,
          const float* __restrict__ bta, f16* __restrict__ outH)
{
    const int row = blockIdx.x * 4 + (threadIdx.x >> 6);
    const int lane = threadIdx.x & 63;
    const float4* xr = (const float4*)(X + (size_t)row * CC);
    float4 v[4];
    float s = 0.f;
#pragma unroll
    for (int i = 0; i < 4; ++i) { v[i] = xr[i * 64 + lane]; s += v[i].x + v[i].y + v[i].z + v[i].w; }
    s = wred(s);
    const float mean = s * (1.f / CC);
    float q = 0.f;
#pragma unroll
    for (int i = 0; i < 4; ++i) {
        float a = v[i].x - mean, b = v[i].y - mean, c = v[i].z - mean, d = v[i].w - mean;
        q += a * a + b * b + c * c + d * d;
    }
    q = wred(q);
    const float rs = rsqrtf(q * (1.f / CC) + 1e-5f);
    const float4* g4 = (const float4*)g;
    const float4* b4 = (const float4*)bta;
    uint2* orow = (uint2*)(outH + (size_t)row * CC);
#pragma unroll
    for (int i = 0; i < 4; ++i) {
        float4 gg = g4[i * 64 + lane], bb = b4[i * 64 + lane];
        union { f16 h4[4]; uint2 u; } pk;
        pk.h4[0] = (f16)((v[i].x - mean) * rs * gg.x + bb.x);
        pk.h4[1] = (f16)((v[i].y - mean) * rs * gg.y + bb.y);
        pk.h4[2] = (f16)((v[i].z - mean) * rs * gg.z + bb.z);
        pk.h4[3] = (f16)((v[i].w - mean) * rs * gg.w + bb.w);
        orow[i * 64 + lane] = pk.u;
    }
}

// ---------------- LN1 + concat(mem, ln(x)) + new_mems write ----------------
__global__ __launch_bounds__(256)
void ln1cat_k(const float* __restrict__ X, const float* __restrict__ memsL,
              const float* __restrict__ g, const float* __restrict__ bta,
              f16* __restrict__ catH, float* __restrict__ nmOut,
              int K, int Kin)
{
    const int row = blockIdx.x * 4 + (threadIdx.x >> 6);  // 0..BB*K-1
    const int lane = threadIdx.x & 63;
    const int b = row / K, rr = row % K;
    uint2* crow = (uint2*)(catH + (size_t)row * CC);
    if (rr < MM) {
        const float4* src = (const float4*)(memsL + ((size_t)b * MM + rr) * CC);
#pragma unroll
        for (int i = 0; i < 4; ++i) {
            float4 vv = src[i * 64 + lane];
            union { f16 h4[4]; uint2 u; } pk;
            pk.h4[0] = (f16)vv.x; pk.h4[1] = (f16)vv.y; pk.h4[2] = (f16)vv.z; pk.h4[3] = (f16)vv.w;
            crow[i * 64 + lane] = pk.u;
        }
        return;
    }
    const float4* xr = (const float4*)(X + ((size_t)b * Kin + (rr - MM)) * CC);
    float4 v[4];
    float s = 0.f;
#pragma unroll
    for (int i = 0; i < 4; ++i) { v[i] = xr[i * 64 + lane]; s += v[i].x + v[i].y + v[i].z + v[i].w; }
    s = wred(s);
    const float mean = s * (1.f / CC);
    float q = 0.f;
#pragma unroll
    for (int i = 0; i < 4; ++i) {
        float a = v[i].x - mean, b2 = v[i].y - mean, c = v[i].z - mean, d = v[i].w - mean;
        q += a * a + b2 * b2 + c * c + d * d;
    }
    q = wred(q);
    const float rs = rsqrtf(q * (1.f / CC) + 1e-5f);
    const float4* g4 = (const float4*)g;
    const float4* b4 = (const float4*)bta;
    float4* nm = nullptr;
    if (rr >= K - MM) nm = (float4*)(nmOut + ((size_t)b * MM + (rr - (K - MM))) * CC);
#pragma unroll
    for (int i = 0; i < 4; ++i) {
        float4 gg = g4[i * 64 + lane], bb = b4[i * 64 + lane];
        float4 o;
        o.x = (v[i].x - mean) * rs * gg.x + bb.x;
        o.y = (v[i].y - mean) * rs * gg.y + bb.y;
        o.z = (v[i].z - mean) * rs * gg.z + bb.z;
        o.w = (v[i].w - mean) * rs * gg.w + bb.w;
        union { f16 h4[4]; uint2 u; } pk;
        pk.h4[0] = (f16)o.x; pk.h4[1] = (f16)o.y; pk.h4[2] = (f16)o.z; pk.h4[3] = (f16)o.w;
        crow[i * 64 + lane] = pk.u;
        if (nm) nm[i * 64 + lane] = o;
    }
}

// ---------------- 128x128 f16 MFMA GEMM: BK=32 2-slot, 32KB LDS -> 3 blocks/CU (TLP) ----------------
// EPI: 0 plain f32, 1 +bias f32, 2 +bias+gelu f16, 3 +bias+res f32, 4 +bias f16
template <int EPI>
__global__ __launch_bounds__(256, 3)
void gemm_k(const f16* __restrict__ A, const f16* __restrict__ BT,
            const float* __restrict__ bias, const float* __restrict__ res,
            float* __restrict__ outF, f16* __restrict__ outH,
            int M, int N, int Kc)
{
    __shared__ f16 sA[2][128 * 32];
    __shared__ f16 sB[2][128 * 32];

    const int nbn = N >> 7;
    const int nwg = gridDim.x;
    const int id = blockIdx.x;
    const int qq = nwg >> 3, r8 = nwg & 7;
    const int xcd = id & 7, pos = id >> 3;
    const int wgid = (xcd < r8 ? xcd * (qq + 1) : r8 * (qq + 1) + (xcd - r8) * qq) + pos;
    const int bm = wgid / nbn, bn = wgid % nbn;

    const int tid = threadIdx.x;
    const int w = tid >> 6, l = tid & 63;
    const int wr = w >> 1, wc = w & 1;
    const int lr = l & 15, lk = (l >> 4) * 8;

    f32x4 acc[4][4] = {};

    const int ar = w * 32 + (l >> 2);      // staging row (inst0); inst1 adds 16
    const int ak = (l & 3) * 8;
    const f16* gA = A + (size_t)(bm * 128 + ar) * Kc + ak;
    const f16* gB = BT + (size_t)(bn * 128 + ar) * Kc + ak;

    auto stage = [&](int slot, int kt) {
        g2lds16(gA + kt, &sA[slot][w * 1024]);
        g2lds16(gA + kt + (size_t)16 * Kc, &sA[slot][w * 1024 + 512]);
        g2lds16(gB + kt, &sB[slot][w * 1024]);
        g2lds16(gB + kt + (size_t)16 * Kc, &sB[slot][w * 1024 + 512]);
    };

    // prologue
    stage(0, 0);
    asm volatile("s_waitcnt vmcnt(0)" ::: "memory");
    __builtin_amdgcn_s_barrier();

    int cur = 0;
    for (int kt = 0; kt < Kc; kt += 32) {
        if (kt + 32 < Kc) stage(cur ^ 1, kt + 32);   // issue next-tile loads FIRST
        f16x8 af[4], bf[4];
#pragma unroll
        for (int mi = 0; mi < 4; ++mi) af[mi] = *(const f16x8*)&sA[cur][(wr * 64 + mi * 16 + lr) * 32 + lk];
#pragma unroll
        for (int ni = 0; ni < 4; ++ni) bf[ni] = *(const f16x8*)&sB[cur][(wc * 64 + ni * 16 + lr) * 32 + lk];
        asm volatile("s_waitcnt lgkmcnt(0)" ::: "memory");
        __builtin_amdgcn_sched_barrier(0);
#pragma unroll
        for (int mi = 0; mi < 4; ++mi)
#pragma unroll
            for (int ni = 0; ni < 4; ++ni)
                acc[mi][ni] = __builtin_amdgcn_mfma_f32_16x16x32_f16(af[mi], bf[ni], acc[mi][ni], 0, 0, 0);
        asm volatile("s_waitcnt vmcnt(0)" ::: "memory");
        __builtin_amdgcn_s_barrier();
        cur ^= 1;
    }

    const int orow0 = bm * 128 + wr * 64 + (l >> 4) * 4;
    const int ocol0 = bn * 128 + wc * 64 + lr;
#pragma unroll
    for (int mi = 0; mi < 4; ++mi)
#pragma unroll
        for (int ni = 0; ni < 4; ++ni) {
            const int col = ocol0 + ni * 16;
            const float bv = (EPI >= 1) ? bias[col] : 0.f;
#pragma unroll
            for (int r = 0; r < 4; ++r) {
                const int row = orow0 + mi * 16 + r;
                float v = acc[mi][ni][r] + bv;
                if (EPI == 2) {
                    const float u = 1.5957691216057308f * (v + 0.044715f * v * v * v);
                    const float e = __expf(u);
                    v = v * e / (e + 1.f);           // 0.5*v*(1+tanh(u/2))
                    outH[(size_t)row * N + col] = (f16)v;
                } else if (EPI == 4) {
                    outH[(size_t)row * N + col] = (f16)v;
                } else if (EPI == 3) {
                    v += res[(size_t)row * N + col];
                    outF[(size_t)row * N + col] = v;
                } else {
                    outF[(size_t)row * N + col] = v;
                }
            }
        }
}

// ---------------- 128x64 f16 MFMA GEMM (proj/fc2): 24KB LDS, 4 blocks/CU ----------------
template <int EPI>
__global__ __launch_bounds__(256, 4)
void gemm64_k(const f16* __restrict__ A, const f16* __restrict__ BT,
              const float* __restrict__ bias, const float* __restrict__ res,
              float* __restrict__ outF, f16* __restrict__ outH,
              int M, int N, int Kc)
{
    __shared__ f16 sA[2][128 * 32];
    __shared__ f16 sB[2][64 * 32];

    const int nbn = N >> 6;
    const int nwg = gridDim.x;
    const int id = blockIdx.x;
    const int qq = nwg >> 3, r8 = nwg & 7;
    const int xcd = id & 7, pos = id >> 3;
    const int wgid = (xcd < r8 ? xcd * (qq + 1) : r8 * (qq + 1) + (xcd - r8) * qq) + pos;
    const int bm = wgid / nbn, bn = wgid % nbn;

    const int tid = threadIdx.x;
    const int w = tid >> 6, l = tid & 63;
    const int wr = w >> 1, wc = w & 1;
    const int lr = l & 15, lk = (l >> 4) * 8;

    f32x4 acc[4][2] = {};

    const int ar = w * 32 + (l >> 2);      // A staging row (inst0); inst1 adds 16
    const int br = w * 16 + (l >> 2);      // B staging row
    const int ak = (l & 3) * 8;
    const f16* gA = A + (size_t)(bm * 128 + ar) * Kc + ak;
    const f16* gB = BT + (size_t)(bn * 64 + br) * Kc + ak;

    auto stage = [&](int slot, int kt) {
        g2lds16(gA + kt, &sA[slot][w * 1024]);
        g2lds16(gA + kt + (size_t)16 * Kc, &sA[slot][w * 1024 + 512]);
        g2lds16(gB + kt, &sB[slot][w * 512]);
    };

    // prologue
    stage(0, 0);
    asm volatile("s_waitcnt vmcnt(0)" ::: "memory");
    __builtin_amdgcn_s_barrier();

    int cur = 0;
    for (int kt = 0; kt < Kc; kt += 32) {
        if (kt + 32 < Kc) stage(cur ^ 1, kt + 32);   // issue next-tile loads FIRST
        f16x8 af[4], bf[2];
#pragma unroll
        for (int mi = 0; mi < 4; ++mi) af[mi] = *(const f16x8*)&sA[cur][(wr * 64 + mi * 16 + lr) * 32 + lk];
#pragma unroll
        for (int ni = 0; ni < 2; ++ni) bf[ni] = *(const f16x8*)&sB[cur][(wc * 32 + ni * 16 + lr) * 32 + lk];
        asm volatile("s_waitcnt lgkmcnt(0)" ::: "memory");
        __builtin_amdgcn_sched_barrier(0);
#pragma unroll
        for (int mi = 0; mi < 4; ++mi)
#pragma unroll
            for (int ni = 0; ni < 2; ++ni)
                acc[mi][ni] = __builtin_amdgcn_mfma_f32_16x16x32_f16(af[mi], bf[ni], acc[mi][ni], 0, 0, 0);
        asm volatile("s_waitcnt vmcnt(0)" ::: "memory");
        __builtin_amdgcn_s_barrier();
        cur ^= 1;
    }

    const int orow0 = bm * 128 + wr * 64 + (l >> 4) * 4;
    const int ocol0 = bn * 64 + wc * 32 + lr;
#pragma unroll
    for (int mi = 0; mi < 4; ++mi)
#pragma unroll
        for (int ni = 0; ni < 2; ++ni) {
            const int col = ocol0 + ni * 16;
            const float bv = (EPI >= 1) ? bias[col] : 0.f;
#pragma unroll
            for (int r = 0; r < 4; ++r) {
                const int row = orow0 + mi * 16 + r;
                float v = acc[mi][ni][r] + bv;
                if (EPI == 3) {
                    v += res[(size_t)row * N + col];
                    outF[(size_t)row * N + col] = v;
                } else if (EPI == 4) {
                    outH[(size_t)row * N + col] = (f16)v;
                } else {
                    outF[(size_t)row * N + col] = v;
                }
            }
        }
}

// ---------------- 256x256 8-phase f16 MFMA GEMM (HK-style schedule), lm_head ----------------
template <int EPI>
__global__ __launch_bounds__(512, 2)
void gemm256_k(const f16* __restrict__ A, const f16* __restrict__ BT,
               const float* __restrict__ bias,
               float* __restrict__ outF, f16* __restrict__ outH,
               int M, int N, int Kc)
{
    __shared__ char ldsbuf[131072];
    char* ldsA = ldsbuf;
    char* ldsB = ldsbuf + 65536;

    // bijective XCD swizzle (m204), bm-fastest for B-panel L2 reuse
    const int nbm = M >> 8;
    const int nwg = gridDim.x;
    int id = blockIdx.x;
    const int qq = nwg >> 3, rr8 = nwg & 7;
    const int xcd = id & 7, pos = id >> 3;
    const int wgid = (xcd < rr8 ? xcd * (qq + 1) : rr8 * (qq + 1) + (xcd - rr8) * qq) + pos;
    const int bm = wgid % nbm, bn = wgid / nbm;

    const int t_ = threadIdx.x;
    const int w = t_ >> 6, l = t_ & 63;
    const int wm = w >> 2, wn = w & 3;
    const int lr = l & 15, lhi = l >> 4;

    const f16* gA = A + (size_t)bm * 256 * Kc;
    const f16* gB = BT + (size_t)bn * 256 * Kc;

    auto stage = [&](const f16* Gbase, char* ldsHalf, int kt) {
#pragma unroll
        for (int ii = 0; ii < 2; ++ii) {
            const int gb = (w << 1) + ii;
            const int s = (gb << 6) + l;
            const int row = s >> 3, grp = s & 7;
            g2lds16(Gbase + (size_t)row * Kc + kt + ((grp ^ (row & 7)) << 3),
                    ldsHalf + gb * 1024);
        }
    };
    auto rdfrag = [&](const char* halfBase, int rowInHalf, int ks) -> f16x8 {
        return *(const f16x8*)(halfBase + rowInHalf * 128 +
                               ((((ks << 2) + lhi) ^ (rowInHalf & 7)) << 4));
    };

    f32x4 acc[8][4] = {};
    f16x8 aA[4][2], blo[2][2], bhi[2][2];

    const int NT = Kc >> 6;
    const char* aHalf0 = ldsA + wm * 16384;
    const char* aHalf1 = ldsA + 32768 + wm * 16384;
    const char* bHalf0 = ldsB + (wn >> 1) * 16384;
    const char* bHalf1 = ldsB + 32768 + (wn >> 1) * 16384;
    const int brow = (wn & 1) * 64;

    // ---- prologue: T0 full + T1 B-halves, drain, publish ----
    stage(gA, ldsA + 0, 0);
    stage(gA + (size_t)128 * Kc, ldsA + 16384, 0);
    stage(gB, ldsB + 0, 0);
    stage(gB + (size_t)128 * Kc, ldsB + 16384, 0);
    stage(gB, ldsB + 32768, 64);
    stage(gB + (size_t)128 * Kc, ldsB + 49152, 64);
    asm volatile("s_waitcnt vmcnt(0)" ::: "memory");
    __builtin_amdgcn_s_barrier();

#define MFMA_QUAD(MQ, NQ, BR)                                                            \
    __builtin_amdgcn_s_setprio(1);                                                       \
    _Pragma("unroll") for (int mf = 0; mf < 4; ++mf)                                     \
    _Pragma("unroll") for (int nf = 0; nf < 2; ++nf)                                     \
    _Pragma("unroll") for (int ks = 0; ks < 2; ++ks)                                     \
        acc[(MQ)*4 + mf][(NQ)*2 + nf] =                                                  \
            __builtin_amdgcn_mfma_f32_16x16x32_f16(aA[mf][ks], BR[nf][ks],               \
                                                   acc[(MQ)*4 + mf][(NQ)*2 + nf], 0, 0, 0); \
    __builtin_amdgcn_s_setprio(0);

#define PHASE_SYNC()                                          \
    __builtin_amdgcn_s_barrier();                             \
    asm volatile("s_waitcnt lgkmcnt(0)" ::: "memory");        \
    __builtin_amdgcn_sched_barrier(0);

    for (int t = 0; t < NT; t += 2) {
        const bool pf0 = (t + 2) < NT;
        const int kb = (t + 1) << 6, kc2 = (t + 2) << 6, kd = (t + 3) << 6;

        // ---- PH1 ----
#pragma unroll
        for (int mf = 0; mf < 4; ++mf)
#pragma unroll
            for (int ks = 0; ks < 2; ++ks) aA[mf][ks] = rdfrag(aHalf0, mf * 16 + lr, ks);
#pragma unroll
        for (int nf = 0; nf < 2; ++nf)
#pragma unroll
            for (int ks = 0; ks < 2; ++ks) blo[nf][ks] = rdfrag(bHalf0, brow + nf * 16 + lr, ks);
        stage(gA, ldsA + 32768, kb);
        PHASE_SYNC();
        MFMA_QUAD(0, 0, blo);
        __builtin_amdgcn_s_barrier();

        // ---- PH2 ----
#pragma unroll
        for (int nf = 0; nf < 2; ++nf)
#pragma unroll
            for (int ks = 0; ks < 2; ++ks) bhi[nf][ks] = rdfrag(bHalf0, brow + 32 + nf * 16 + lr, ks);
        stage(gA + (size_t)128 * Kc, ldsA + 49152, kb);
        PHASE_SYNC();
        MFMA_QUAD(0, 1, bhi);
        __builtin_amdgcn_s_barrier();

        // ---- PH3 ----
#pragma unroll
        for (int mf = 0; mf < 4; ++mf)
#pragma unroll
            for (int ks = 0; ks < 2; ++ks) aA[mf][ks] = rdfrag(aHalf0, 64 + mf * 16 + lr, ks);
        if (pf0) stage(gB, ldsB + 0, kc2);
        PHASE_SYNC();
        MFMA_QUAD(1, 0, blo);
        __builtin_amdgcn_s_barrier();

        // ---- PH4 ----
        if (pf0) {
            stage(gB + (size_t)128 * Kc, ldsB + 16384, kc2);
            asm volatile("s_waitcnt vmcnt(4)" ::: "memory");
        } else {
            asm volatile("s_waitcnt vmcnt(0)" ::: "memory");
        }
        PHASE_SYNC();
        MFMA_QUAD(1, 1, bhi);
        __builtin_amdgcn_s_barrier();

        // ---- PH5 ----
#pragma unroll
        for (int mf = 0; mf < 4; ++mf)
#pragma unroll
            for (int ks = 0; ks < 2; ++ks) aA[mf][ks] = rdfrag(aHalf1, mf * 16 + lr, ks);
#pragma unroll
        for (int nf = 0; nf < 2; ++nf)
#pragma unroll
            for (int ks = 0; ks < 2; ++ks) blo[nf][ks] = rdfrag(bHalf1, brow + nf * 16 + lr, ks);
        if (pf0) stage(gA, ldsA + 0, kc2);
        PHASE_SYNC();
        MFMA_QUAD(0, 0, blo);
        __builtin_amdgcn_s_barrier();

        // ---- PH6 ----
#pragma unroll
        for (int nf = 0; nf < 2; ++nf)
#pragma unroll
            for (int ks = 0; ks < 2; ++ks) bhi[nf][ks] = rdfrag(bHalf1, brow + 32 + nf * 16 + lr, ks);
        if (pf0) stage(gA + (size_t)128 * Kc, ldsA + 16384, kc2);
        PHASE_SYNC();
        MFMA_QUAD(0, 1, bhi);
        __builtin_amdgcn_s_barrier();

        // ---- PH7 ----
#pragma unroll
        for (int mf = 0; mf < 4; ++mf)
#pragma unroll
            for (int ks = 0; ks < 2; ++ks) aA[mf][ks] = rdfrag(aHalf1, 64 + mf * 16 + lr, ks);
        if (pf0) stage(gB, ldsB + 32768, kd);
        PHASE_SYNC();
        MFMA_QUAD(1, 0, blo);
        __builtin_amdgcn_s_barrier();

        // ---- PH8 ----
        if (pf0) {
            stage(gB + (size_t)128 * Kc, ldsB + 49152, kd);
            asm volatile("s_waitcnt vmcnt(4)" ::: "memory");
        } else {
            asm volatile("s_waitcnt vmcnt(0)" ::: "memory");
        }
        PHASE_SYNC();
        MFMA_QUAD(1, 1, bhi);
        __builtin_amdgcn_s_barrier();
    }
#undef MFMA_QUAD
#undef PHASE_SYNC

    // ---- epilogue (direct stores) ----
    const int rb0 = bm * 256 + wm * 128 + lhi * 4;
    const int cb0 = bn * 256 + wn * 64 + lr;
#pragma unroll
    for (int mf = 0; mf < 8; ++mf)
#pragma unroll
        for (int nf = 0; nf < 4; ++nf) {
            const int col = cb0 + nf * 16;
            const float bv = (EPI >= 1) ? bias[col] : 0.f;
#pragma unroll
            for (int r = 0; r < 4; ++r) {
                const int row = rb0 + mf * 16 + r;
                float v = acc[mf][nf][r] + bv;
                if (EPI == 4) {
                    outH[(size_t)row * N + col] = (f16)v;
                } else {
                    outF[(size_t)row * N + col] = v;
                }
            }
        }
}

// ---------------- attention: MFMA flash, defer-max, double-buffered K/Vt (1 barrier/tile) ----------------
__global__ __launch_bounds__(256)
void attn_k(const f16* __restrict__ qkv, const float* __restrict__ remb,
            const float* __restrict__ rbias, f16* __restrict__ yH, int K)
{
    __shared__ f16 K_lds[2][64 * 64];
    __shared__ f16 Vt_lds[2][64 * 64];
    __shared__ f16 P_lds[64 * 64];
    __shared__ float s_s[66];

    const int b = blockIdx.x >> 4, h = blockIdx.x & 15;
    const int i0 = blockIdx.y * 64;
    const int t = threadIdx.x;
    const int w = t >> 6, l = t & 63;
    const int c = l & 15, g = l >> 4;

    const f16* qg = qkv + (size_t)b * K * 3072 + h * 64;
    const f16* kg = qg + 1024;
    const f16* vg = qg + 2048;
    const float* rb = rbias + h * 64;
    const float* re = remb + h * 64;

    const int kb = t >> 4, db = t & 15;

    auto stageK = [&](int j0, int slot) {
#pragma unroll
        for (int i = 0; i < 2; ++i) {
            const int s = w * 128 + i * 64 + l;
            const int row = s >> 3, grp = s & 7;
            g2lds16(kg + (size_t)(j0 + row) * 3072 + ((grp ^ (row & 7)) * 8),
                    (char*)K_lds[slot] + (size_t)(w * 128 + i * 64) * 16);
        }
    };
    auto loadV = [&](int j0, uint2* rowv) {
#pragma unroll
        for (int i = 0; i < 4; ++i)
            rowv[i] = *(const uint2*)(vg + (size_t)(j0 + kb * 4 + i) * 3072 + db * 4);
    };
    auto writeVt = [&](const uint2* rowvu, int slot) {
#pragma unroll
        for (int j = 0; j < 4; ++j) {
            union { uint2 u; f16 hh[4]; } colv;
#pragma unroll
            for (int i = 0; i < 4; ++i) {
                union { uint2 u; f16 hh[4]; } rv; rv.u = rowvu[i];
                colv.hh[i] = rv.hh[j];
            }
            const int d = db * 4 + j;
            *(uint2*)((char*)Vt_lds[slot] + d * 128 + ((kb * 8) ^ ((d & 7) << 4))) = colv.u;
        }
    };

    f16x8 qf[2];
    {
        const int qrow = i0 + w * 16 + c;
#pragma unroll
        for (int ks = 0; ks < 2; ++ks) {
            f16x8 raw = *(const f16x8*)(qg + (size_t)qrow * 3072 + ks * 32 + g * 8);
            f16x8 o;
#pragma unroll
            for (int j = 0; j < 8; ++j) o[j] = (f16)((float)raw[j] + rb[ks * 32 + g * 8 + j]);
            qf[ks] = o;
        }
    }
    if (t < 65) {
        float sv = 0.f;
        const int i = i0 + t;
        if (i < K) {
            const f16* qr = qg + (size_t)i * 3072;
#pragma unroll
            for (int d8 = 0; d8 < 8; ++d8) {
                f16x8 v8 = *(const f16x8*)(qr + d8 * 8);
#pragma unroll
                for (int j = 0; j < 8; ++j) sv += ((float)v8[j] + rb[d8 * 8 + j]) * re[d8 * 8 + j];
            }
        }
        s_s[t] = sv;
    }

    {
        uint2 rowv[4];
        stageK(0, 0);
        loadV(0, rowv);
        writeVt(rowv, 0);
    }
    __syncthreads();

    float sA[4], sB[4];
#pragma unroll
    for (int r = 0; r < 4; ++r) {
        sA[r] = s_s[w * 16 + g * 4 + r];
        sB[r] = s_s[w * 16 + g * 4 + r + 1];
    }

    float m_run[4] = {0.f, 0.f, 0.f, 0.f};
    float psum[4] = {0.f, 0.f, 0.f, 0.f};
    f32x4 yacc[4] = {};

    int cur = 0;
    for (int j0 = 0; j0 < K; j0 += 64, cur ^= 1) {
        const bool more = (j0 + 64) < K;
        uint2 rowv[4];
        if (more) { stageK(j0 + 64, cur ^ 1); loadV(j0 + 64, rowv); }

        f32x4 sc[4] = {};
#pragma unroll
        for (int tt = 0; tt < 4; ++tt) {
            const int row = tt * 16 + c;
#pragma unroll
            for (int ks = 0; ks < 2; ++ks) {
                f16x8 kf = *(const f16x8*)((char*)K_lds[cur] + row * 128 + ((ks * 64 + g * 16) ^ ((row & 7) << 4)));
                sc[tt] = __builtin_amdgcn_mfma_f32_16x16x32_f16(qf[ks], kf, sc[tt], 0, 0, 0);
            }
        }

        float p[4][4];
#pragma unroll
        for (int tt = 0; tt < 4; ++tt)
#pragma unroll
            for (int r = 0; r < 4; ++r) {
                const int gi = i0 + w * 16 + g * 4 + r;
                const int gj = j0 + tt * 16 + c;
                const float bd = (gj <= gi) ? sA[r] : ((gj == gi + 1) ? 0.f : sB[r]);
                p[tt][r] = (sc[tt][r] + bd) * 0.125f;
            }

        float lmax[4];
        bool need = false;
#pragma unroll
        for (int r = 0; r < 4; ++r) {
            lmax[r] = fmaxf(fmaxf(p[0][r], p[1][r]), fmaxf(p[2][r], p[3][r]));
            need |= (lmax[r] > m_run[r] + 8.f);
        }
        if (__any(need)) {
#pragma unroll
            for (int r = 0; r < 4; ++r) {
                float mx = lmax[r];
                mx = fmaxf(mx, __shfl_xor(mx, 1));
                mx = fmaxf(mx, __shfl_xor(mx, 2));
                mx = fmaxf(mx, __shfl_xor(mx, 4));
                mx = fmaxf(mx, __shfl_xor(mx, 8));
                if (mx > m_run[r]) {
                    const float f = __expf(m_run[r] - mx);
                    m_run[r] = mx;
                    psum[r] *= f;
#pragma unroll
                    for (int tt = 0; tt < 4; ++tt) yacc[tt][r] *= f;
                }
            }
        }
#pragma unroll
        for (int r = 0; r < 4; ++r) {
            float ss = 0.f;
#pragma unroll
            for (int tt = 0; tt < 4; ++tt) {
                const float e = __expf(p[tt][r] - m_run[r]);
                p[tt][r] = e;
                ss += e;
            }
            psum[r] += ss;
        }

        if (more) writeVt(rowv, cur ^ 1);
#pragma unroll
        for (int tt = 0; tt < 4; ++tt)
#pragma unroll
            for (int r = 0; r < 4; ++r) {
                const int q = w * 16 + g * 4 + r;
                *(f16*)((char*)P_lds + q * 128 + (((tt * 16 + c) * 2) ^ ((q & 7) << 4))) = (f16)p[tt][r];
            }
        asm volatile("s_waitcnt lgkmcnt(0)" ::: "memory");
        __builtin_amdgcn_sched_barrier(0);

        {
            const int qrow = w * 16 + c;
            f16x8 pa[2];
#pragma unroll
            for (int ks = 0; ks < 2; ++ks)
                pa[ks] = *(const f16x8*)((char*)P_lds + qrow * 128 + ((ks * 64 + g * 16) ^ ((qrow & 7) << 4)));
#pragma unroll
            for (int tt = 0; tt < 4; ++tt) {
                const int drow = tt * 16 + c;
#pragma unroll
                for (int ks = 0; ks < 2; ++ks) {
                    f16x8 vb = *(const f16x8*)((char*)Vt_lds[cur] + drow * 128 + ((ks * 64 + g * 16) ^ ((drow & 7) << 4)));
                    yacc[tt] = __builtin_amdgcn_mfma_f32_16x16x32_f16(pa[ks], vb, yacc[tt], 0, 0, 0);
                }
            }
        }
        __syncthreads();
    }

#pragma unroll
    for (int r = 0; r < 4; ++r) {
        float ps = psum[r];
        ps += __shfl_xor(ps, 1);
        ps += __shfl_xor(ps, 2);
        ps += __shfl_xor(ps, 4);
        ps += __shfl_xor(ps, 8);
        const float inv = 1.f / ps;
        const int row = i0 + w * 16 + g * 4 + r;
        f16* dst = yH + (size_t)(b * K + row) * CC + h * 64;
#pragma unroll
        for (int tt = 0; tt < 4; ++tt)
            dst[tt * 16 + c] = (f16)(yacc[tt][r] * inv);
    }
}

// ---------------- host ----------------
extern "C" void kernel_launch(void* const* d_in, const int* in_sizes, int n_in,
                              void* d_out, int out_size, void* d_ws, size_t ws_size,
                              hipStream_t stream)
{
    (void)in_sizes; (void)n_in; (void)out_size; (void)ws_size;
    const int*   idx    = (const int*)  d_in[0];
    const float* mems   = (const float*)d_in[1];
    const float* wte    = (const float*)d_in[2];
    const float* ln1_g  = (const float*)d_in[3];
    const float* ln1_b  = (const float*)d_in[4];
    const float* attn_w = (const float*)d_in[5];
    const float* attn_b = (const float*)d_in[6];
    const float* proj_w = (const float*)d_in[7];
    const float* proj_b = (const float*)d_in[8];
    const float* r_emb  = (const float*)d_in[9];
    const float* r_bias = (const float*)d_in[10];
    const float* ln2_g  = (const float*)d_in[11];
    const float* ln2_b  = (const float*)d_in[12];
    const float* fc_w   = (const float*)d_in[13];
    const float* fc_b   = (const float*)d_in[14];
    const float* fc2_w  = (const float*)d_in[15];
    const float* fc2_b  = (const float*)d_in[16];
    const float* lnf_g  = (const float*)d_in[17];
    const float* lnf_b  = (const float*)d_in[18];
    const float* lm_w   = (const float*)d_in[19];
    float* out = (float*)d_out;

    char* wp = (char*)d_ws; size_t off = 0;
    auto carve = [&](size_t bytes) -> void* {
        void* p = wp + off; off += (bytes + 255) & ~(size_t)255; return p;
    };
    const int KMAX = TT + LNUM * MM;  // 1792
    f16*  attn_wT = (f16*) carve((size_t)LNUM * 3 * CC * CC * 2);
    f16*  proj_wT = (f16*) carve((size_t)LNUM * CC * CC * 2);
    f16*  fc_wT   = (f16*) carve((size_t)LNUM * 4 * CC * CC * 2);
    f16*  fc2_wT  = (f16*) carve((size_t)LNUM * 4 * CC * CC * 2);
    f16*  lm_wT   = (f16*) carve((size_t)VV * CC * 2);
    float* x0     = (float*)carve((size_t)BB * KMAX * CC * 4);
    float* x1     = (float*)carve((size_t)BB * KMAX * CC * 4);
    f16*  catH    = (f16*) carve((size_t)BB * KMAX * CC * 2);
    f16*  qkv16   = (f16*) carve((size_t)BB * KMAX * 3 * CC * 2);
    f16*  yH      = (f16*) carve((size_t)BB * KMAX * CC * 2);
    float* yp     = (float*)carve((size_t)BB * KMAX * CC * 4);
    f16*  h2H     = (f16*) carve((size_t)BB * KMAX * CC * 2);
    f16*  a1H     = (f16*) carve((size_t)BB * KMAX * 4 * CC * 2);
    f16*  xfH     = (f16*) carve((size_t)BB * KMAX * CC * 2);

    // weight transposes (f32 -> f16, (R,Cc) -> (Cc,R)), 64x64 tiles
    transpose_k<<<dim3(3 * CC / 64, CC / 64, LNUM), 256, 0, stream>>>(attn_w, attn_wT, CC, 3 * CC);
    transpose_k<<<dim3(CC / 64, CC / 64, LNUM),     256, 0, stream>>>(proj_w, proj_wT, CC, CC);
    transpose_k<<<dim3(4 * CC / 64, CC / 64, LNUM), 256, 0, stream>>>(fc_w, fc_wT, CC, 4 * CC);
    transpose_k<<<dim3(CC / 64, 4 * CC / 64, LNUM), 256, 0, stream>>>(fc2_w, fc2_wT, 4 * CC, CC);
    transpose_k<<<dim3(VV / 64, CC / 64, 1),        256, 0, stream>>>(lm_w, lm_wT, CC, VV);

    embed_k<<<BB * TT, 256, 0, stream>>>(idx, wte, x0);

    const size_t LOGITS = (size_t)BB * KMAX * VV;
    float* xcur = x0; float* xnxt = x1;
    for (int l = 0; l < LNUM; ++l) {
        const int Kin = TT + MM * l;
        const int K = Kin + MM;
        const int Mrows = BB * K;
        const int nbm128 = Mrows / 128;
        ln1cat_k<<<Mrows / 4, 256, 0, stream>>>(xcur, mems + (size_t)l * BB * MM * CC,
                                                ln1_g + l * CC, ln1_b + l * CC,
                                                catH, out + LOGITS + (size_t)l * BB * MM * CC, K, Kin);
        gemm_k<4><<<(3 * CC / 128) * nbm128, 256, 0, stream>>>(
            catH, attn_wT + (size_t)l * 3 * CC * CC, attn_b + (size_t)l * 3 * CC, nullptr,
            nullptr, qkv16, Mrows, 3 * CC, CC);
        attn_k<<<dim3(BB * HH, K / 64), 256, 0, stream>>>(
            qkv16, r_emb + (size_t)l * HH * DHH, r_bias + (size_t)l * HH * DHH, yH, K);
        gemm64_k<1><<<(CC / 64) * nbm128, 256, 0, stream>>>(
            yH, proj_wT + (size_t)l * CC * CC, proj_b + (size_t)l * CC, nullptr,
            yp, nullptr, Mrows, CC, CC);
        ln_k<<<Mrows / 4, 256, 0, stream>>>(yp, ln2_g + l * CC, ln2_b + l * CC, h2H);
        gemm_k<2><<<(4 * CC / 128) * nbm128, 256, 0, stream>>>(
            h2H, fc_wT + (size_t)l * 4 * CC * CC, fc_b + (size_t)l * 4 * CC, nullptr,
            nullptr, a1H, Mrows, 4 * CC, CC);
        gemm64_k<3><<<(CC / 64) * nbm128, 256, 0, stream>>>(
            a1H, fc2_wT + (size_t)l * 4 * CC * CC, fc2_b + (size_t)l * CC, yp,
            xnxt, nullptr, Mrows, CC, 4 * CC);
        float* tmp = xcur; xcur = xnxt; xnxt = tmp;
    }
    ln_k<<<(BB * KMAX) / 4, 256, 0, stream>>>(xcur, lnf_g, lnf_b, xfH);
    gemm256_k<0><<<(BB * KMAX / 256) * (VV / 256), 512, 0, stream>>>(
        xfH, lm_wT, nullptr, out, nullptr, BB * KMAX, VV, CC);
}